// Round 8
// baseline (11933.992 us; speedup 1.0000x reference)
//
#include <hip/hip_runtime.h>
#include <math.h>

// ESBN: encoder (conv x3 + linear) + 64-step LSTM/memory scan. fp32.
// R8: scan = ONE kernel per step (phase A: step-t outputs, redundantly per
// b-slice; phase B: gates GEMM for t+1 from LDS-resident [kx|h]).
// G and C double-buffered to kill cross-block races. XC buffer eliminated.
// Encoder: R6 split (conv1 -> c1g chunks -> enc2), measured best.

__device__ __forceinline__ float sigm(float x) { return 1.0f / (1.0f + expf(-x)); }

// ---------------------------------------------------------------------------
// prep: transposed weights in ws.
//   WT [580][2048] (rows 0..64 w_ih^T, 65..576 w_hh^T, 577..579 zero),
//   bsum[2048], w1T[48][32], w2T[512][64], w3T[1024][64], ewT[256][64]
// ---------------------------------------------------------------------------
#define PREP_N (1187840 + 2048 + 1536 + 32768 + 65536 + 16384)
__global__ __launch_bounds__(256) void prep_kernel(
    const float* __restrict__ w_ih, const float* __restrict__ w_hh,
    const float* __restrict__ b_ih, const float* __restrict__ b_hh,
    const float* __restrict__ w1, const float* __restrict__ w2,
    const float* __restrict__ w3, const float* __restrict__ ew,
    float* __restrict__ WT, float* __restrict__ bsum,
    float* __restrict__ w1T, float* __restrict__ w2T,
    float* __restrict__ w3T, float* __restrict__ ewT)
{
  int i = blockIdx.x * 256 + threadIdx.x;
  if (i < 1187840) {
    const int r = i >> 11, c = i & 2047;
    float v;
    if (r < 65)       v = w_ih[(size_t)c * 65 + r];
    else if (r < 577) v = w_hh[(size_t)c * 512 + (r - 65)];
    else              v = 0.0f;
    WT[i] = v; return;
  }
  i -= 1187840;
  if (i < 2048) { bsum[i] = b_ih[i] + b_hh[i]; return; }
  i -= 2048;
  if (i < 1536) { const int r = i >> 5, oc = i & 31; w1T[i] = w1[oc * 48 + r]; return; }
  i -= 1536;
  if (i < 32768) { const int r = i >> 6, oc = i & 63; w2T[i] = w2[oc * 512 + r]; return; }
  i -= 32768;
  if (i < 65536) { const int r = i >> 6, oc = i & 63; w3T[i] = w3[oc * 1024 + r]; return; }
  i -= 65536;
  if (i < 16384) { const int k = i >> 6, d = i & 63; ewT[i] = ew[d * 256 + k]; return; }
}

// ---------------------------------------------------------------------------
// E1: conv1 (3->32, k4 s2, out 15x15, ReLU), one block per sample.
// LDS = image only (12 KB). Output c1g[bid][32][240] (row stride 16).
// ---------------------------------------------------------------------------
#define ENT 192
__global__ __launch_bounds__(ENT) void conv1_kernel(
    const float* __restrict__ images,
    const float* __restrict__ w1T, const float* __restrict__ b1,
    float* __restrict__ c1g, const int s0)
{
  __shared__ __align__(16) float buf[3072];
  const int bid = blockIdx.x;
  const int tid = threadIdx.x;
  {
    const float4* src = (const float4*)(images + (size_t)(s0 + bid) * 3072);
    float4* dst = (float4*)buf;
    for (int i = tid; i < 768; i += ENT) dst[i] = src[i];
  }
  __syncthreads();

  float* outp = c1g + (size_t)bid * 7680;
  for (int s = tid; s < 360; s += ENT) {
    const int ocg  = s & 7;
    const int pg   = s >> 3;
    const int row  = pg / 3;
    const int colg = pg - row * 3;
    const int ox0  = colg * 5;
    float acc[4][5];
    #pragma unroll
    for (int o = 0; o < 4; ++o) {
      const float bb = b1[ocg * 4 + o];
      #pragma unroll
      for (int p = 0; p < 5; ++p) acc[o][p] = bb;
    }
    #pragma unroll
    for (int ic = 0; ic < 3; ++ic) {
      #pragma unroll
      for (int ky = 0; ky < 4; ++ky) {
        const int y = 2 * row + ky;
        const float* ib = &buf[ic * 1024 + y * 32 + 2 * ox0];
        float v[12];
        #pragma unroll
        for (int i = 0; i < 6; ++i) { float2 t2 = *(const float2*)(ib + 2 * i); v[2*i] = t2.x; v[2*i+1] = t2.y; }
        float w_[4][4];
        #pragma unroll
        for (int kx = 0; kx < 4; ++kx)
          *(float4*)&w_[kx][0] = *(const float4*)(w1T + (ic * 16 + ky * 4 + kx) * 32 + ocg * 4);
        #pragma unroll
        for (int o = 0; o < 4; ++o)
          #pragma unroll
          for (int p = 0; p < 5; ++p)
            acc[o][p] += w_[0][o] * v[2*p] + w_[1][o] * v[2*p+1] + w_[2][o] * v[2*p+2] + w_[3][o] * v[2*p+3];
      }
    }
    #pragma unroll
    for (int o = 0; o < 4; ++o)
      #pragma unroll
      for (int p = 0; p < 5; ++p)
        outp[(ocg * 4 + o) * 240 + row * 16 + ox0 + p] = fmaxf(acc[o][p], 0.0f);
  }
}

// ---------------------------------------------------------------------------
// E2: conv2 + conv3 + linear, one block per sample.
// LDS: c1 [32][240] (30 KB) + c2 [64][37] (9.25 KB) -> 4 blk/CU.
// ---------------------------------------------------------------------------
__global__ __launch_bounds__(ENT) void enc2_kernel(
    const float* __restrict__ c1g,
    const float* __restrict__ w2T, const float* __restrict__ b2,
    const float* __restrict__ w3T, const float* __restrict__ b3,
    const float* __restrict__ ewT, const float* __restrict__ eb,
    float* __restrict__ z_all, const int s0)
{
  __shared__ __align__(16) float c1[7680];
  __shared__ __align__(16) float buf[2368];
  const int bid = blockIdx.x;
  const int tid = threadIdx.x;

  {
    const float4* src = (const float4*)(c1g + (size_t)bid * 7680);
    float4* dst = (float4*)c1;
    for (int i = tid; i < 1920; i += ENT) dst[i] = src[i];
  }
  __syncthreads();

  // conv2: 32->64, k4 s2, out 6x6, ReLU. tile = 4oc x 3pos. 192 slots.
  {
    const int ocg = tid & 15;
    const int pg  = tid >> 4;
    const int row = pg >> 1;
    const int ox0 = (pg & 1) * 3;
    float acc[4][3];
    #pragma unroll
    for (int o = 0; o < 4; ++o) {
      const float bb = b2[ocg * 4 + o];
      acc[o][0] = bb; acc[o][1] = bb; acc[o][2] = bb;
    }
    for (int ic = 0; ic < 32; ++ic) {
      #pragma unroll
      for (int ky = 0; ky < 4; ++ky) {
        const int y = 2 * row + ky;
        const float* ib = &c1[ic * 240 + y * 16 + 2 * ox0];
        float v[8];
        #pragma unroll
        for (int i = 0; i < 4; ++i) { float2 t2 = *(const float2*)(ib + 2 * i); v[2*i] = t2.x; v[2*i+1] = t2.y; }
        float w_[4][4];
        #pragma unroll
        for (int kx = 0; kx < 4; ++kx)
          *(float4*)&w_[kx][0] = *(const float4*)(w2T + (ic * 16 + ky * 4 + kx) * 64 + ocg * 4);
        #pragma unroll
        for (int o = 0; o < 4; ++o)
          #pragma unroll
          for (int p = 0; p < 3; ++p)
            acc[o][p] += w_[0][o] * v[2*p] + w_[1][o] * v[2*p+1] + w_[2][o] * v[2*p+2] + w_[3][o] * v[2*p+3];
      }
    }
    #pragma unroll
    for (int o = 0; o < 4; ++o)
      #pragma unroll
      for (int p = 0; p < 3; ++p)
        buf[(ocg * 4 + o) * 37 + row * 6 + ox0 + p] = fmaxf(acc[o][p], 0.0f);
  }
  __syncthreads();

  // conv3: 64->64, k4 s2, out 2x2, NO ReLU. thread = oc(64) x kc(3).
  {
    const int oc = tid & 63;
    const int kc = tid >> 6;
    const int k0 = (kc * 256) / 3, k1 = ((kc + 1) * 256) / 3;
    float acc[4] = {0.f, 0.f, 0.f, 0.f};
    for (int it = k0; it < k1; ++it) {
      const int ic = it >> 2;
      const int ky = it & 3;
      float v[2][6];
      #pragma unroll
      for (int oy = 0; oy < 2; ++oy) {
        const float* ib = &buf[ic * 37 + (2 * oy + ky) * 6];
        #pragma unroll
        for (int i = 0; i < 3; ++i) { float2 t2 = *(const float2*)(ib + 2 * i); v[oy][2*i] = t2.x; v[oy][2*i+1] = t2.y; }
      }
      float w_[4];
      #pragma unroll
      for (int kx = 0; kx < 4; ++kx) w_[kx] = w3T[(ic * 16 + ky * 4 + kx) * 64 + oc];
      #pragma unroll
      for (int p = 0; p < 4; ++p) {
        const int oy = p >> 1, ox = p & 1;
        acc[p] += w_[0] * v[oy][2*ox] + w_[1] * v[oy][2*ox+1] + w_[2] * v[oy][2*ox+2] + w_[3] * v[oy][2*ox+3];
      }
    }
    #pragma unroll
    for (int p = 0; p < 4; ++p) c1[kc * 260 + p * 64 + oc] = acc[p];
  }
  __syncthreads();

  for (int o = tid; o < 256; o += ENT) {
    const int oc = o >> 2, p = o & 3;
    c1[1024 + o] = b3[oc] + c1[p * 64 + oc] + c1[260 + p * 64 + oc] + c1[520 + p * 64 + oc];
  }
  __syncthreads();

  {
    const int d  = tid & 63;
    const int kc = tid >> 6;
    const int k0 = (kc * 256) / 3, k1 = ((kc + 1) * 256) / 3;
    float s = 0.0f;
    for (int k = k0; k < k1; ++k) s += ewT[k * 64 + d] * c1[1024 + k];
    c1[1536 + kc * 64 + d] = s;
  }
  __syncthreads();
  if (tid < 64) {
    z_all[(size_t)(s0 + bid) * 64 + tid] = eb[tid] + c1[1536 + tid] + c1[1600 + tid] + c1[1664 + tid];
  }
}

// ---------------------------------------------------------------------------
// Monolithic encoder fallback (if ws can't hold c1g chunks).
// ---------------------------------------------------------------------------
__global__ __launch_bounds__(ENT) void encoder_kernel(
    const float* __restrict__ images,
    const float* __restrict__ w1T, const float* __restrict__ b1,
    const float* __restrict__ w2T, const float* __restrict__ b2,
    const float* __restrict__ w3T, const float* __restrict__ b3,
    const float* __restrict__ ewT, const float* __restrict__ eb,
    float* __restrict__ z_all)
{
  __shared__ __align__(16) float c1[7744];
  __shared__ __align__(16) float buf[3072];
  const int bid = blockIdx.x;
  const int tid = threadIdx.x;
  {
    const float4* src = (const float4*)(images + (size_t)bid * 3072);
    float4* dst = (float4*)buf;
    for (int i = tid; i < 768; i += ENT) dst[i] = src[i];
  }
  __syncthreads();
  for (int s = tid; s < 360; s += ENT) {
    const int ocg  = s & 7;
    const int pg   = s >> 3;
    const int row  = pg / 3;
    const int colg = pg - row * 3;
    const int ox0  = colg * 5;
    float acc[4][5];
    #pragma unroll
    for (int o = 0; o < 4; ++o) {
      const float bb = b1[ocg * 4 + o];
      #pragma unroll
      for (int p = 0; p < 5; ++p) acc[o][p] = bb;
    }
    #pragma unroll
    for (int ic = 0; ic < 3; ++ic) {
      #pragma unroll
      for (int ky = 0; ky < 4; ++ky) {
        const int y = 2 * row + ky;
        const float* ib = &buf[ic * 1024 + y * 32 + 2 * ox0];
        float v[12];
        #pragma unroll
        for (int i = 0; i < 6; ++i) { float2 t2 = *(const float2*)(ib + 2 * i); v[2*i] = t2.x; v[2*i+1] = t2.y; }
        float w_[4][4];
        #pragma unroll
        for (int kx = 0; kx < 4; ++kx)
          *(float4*)&w_[kx][0] = *(const float4*)(w1T + (ic * 16 + ky * 4 + kx) * 32 + ocg * 4);
        #pragma unroll
        for (int o = 0; o < 4; ++o)
          #pragma unroll
          for (int p = 0; p < 5; ++p)
            acc[o][p] += w_[0][o] * v[2*p] + w_[1][o] * v[2*p+1] + w_[2][o] * v[2*p+2] + w_[3][o] * v[2*p+3];
      }
    }
    #pragma unroll
    for (int o = 0; o < 4; ++o)
      #pragma unroll
      for (int p = 0; p < 5; ++p)
        c1[(ocg * 4 + o) * 242 + row * 16 + ox0 + p] = fmaxf(acc[o][p], 0.0f);
  }
  __syncthreads();
  {
    const int ocg = tid & 15;
    const int pg  = tid >> 4;
    const int row = pg >> 1;
    const int ox0 = (pg & 1) * 3;
    float acc[4][3];
    #pragma unroll
    for (int o = 0; o < 4; ++o) {
      const float bb = b2[ocg * 4 + o];
      acc[o][0] = bb; acc[o][1] = bb; acc[o][2] = bb;
    }
    for (int ic = 0; ic < 32; ++ic) {
      #pragma unroll
      for (int ky = 0; ky < 4; ++ky) {
        const int y = 2 * row + ky;
        const float* ib = &c1[ic * 242 + y * 16 + 2 * ox0];
        float v[8];
        #pragma unroll
        for (int i = 0; i < 4; ++i) { float2 t2 = *(const float2*)(ib + 2 * i); v[2*i] = t2.x; v[2*i+1] = t2.y; }
        float w_[4][4];
        #pragma unroll
        for (int kx = 0; kx < 4; ++kx)
          *(float4*)&w_[kx][0] = *(const float4*)(w2T + (ic * 16 + ky * 4 + kx) * 64 + ocg * 4);
        #pragma unroll
        for (int o = 0; o < 4; ++o)
          #pragma unroll
          for (int p = 0; p < 3; ++p)
            acc[o][p] += w_[0][o] * v[2*p] + w_[1][o] * v[2*p+1] + w_[2][o] * v[2*p+2] + w_[3][o] * v[2*p+3];
      }
    }
    __syncthreads();
    #pragma unroll
    for (int o = 0; o < 4; ++o)
      #pragma unroll
      for (int p = 0; p < 3; ++p)
        buf[(ocg * 4 + o) * 38 + row * 6 + ox0 + p] = fmaxf(acc[o][p], 0.0f);
  }
  __syncthreads();
  {
    const int oc = tid & 63;
    const int kc = tid >> 6;
    const int k0 = (kc * 256) / 3, k1 = ((kc + 1) * 256) / 3;
    float acc[4] = {0.f, 0.f, 0.f, 0.f};
    for (int it = k0; it < k1; ++it) {
      const int ic = it >> 2;
      const int ky = it & 3;
      float v[2][6];
      #pragma unroll
      for (int oy = 0; oy < 2; ++oy) {
        const float* ib = &buf[ic * 38 + (2 * oy + ky) * 6];
        #pragma unroll
        for (int i = 0; i < 3; ++i) { float2 t2 = *(const float2*)(ib + 2 * i); v[oy][2*i] = t2.x; v[oy][2*i+1] = t2.y; }
      }
      float w_[4];
      #pragma unroll
      for (int kx = 0; kx < 4; ++kx) w_[kx] = w3T[(ic * 16 + ky * 4 + kx) * 64 + oc];
      #pragma unroll
      for (int p = 0; p < 4; ++p) {
        const int oy = p >> 1, ox = p & 1;
        acc[p] += w_[0] * v[oy][2*ox] + w_[1] * v[oy][2*ox+1] + w_[2] * v[oy][2*ox+2] + w_[3] * v[oy][2*ox+3];
      }
    }
    #pragma unroll
    for (int p = 0; p < 4; ++p) c1[kc * 260 + p * 64 + oc] = acc[p];
  }
  __syncthreads();
  for (int o = tid; o < 256; o += ENT) {
    const int oc = o >> 2, p = o & 3;
    c1[1024 + o] = b3[oc] + c1[p * 64 + oc] + c1[260 + p * 64 + oc] + c1[520 + p * 64 + oc];
  }
  __syncthreads();
  {
    const int d  = tid & 63;
    const int kc = tid >> 6;
    const int k0 = (kc * 256) / 3, k1 = ((kc + 1) * 256) / 3;
    float s = 0.0f;
    for (int k = k0; k < k1; ++k) s += ewT[k * 64 + d] * c1[1024 + k];
    c1[1536 + kc * 64 + d] = s;
  }
  __syncthreads();
  if (tid < 64) {
    z_all[(size_t)bid * 64 + tid] = eb[tid] + c1[1536 + tid] + c1[1600 + tid] + c1[1664 + tid];
  }
}

// ---------------------------------------------------------------------------
// z-Gram: z_gram[b][t][n] = z_t . z_n
// ---------------------------------------------------------------------------
__global__ __launch_bounds__(256) void gram_kernel(
    const float* __restrict__ z_all, float* __restrict__ z_gram)
{
  const int b = blockIdx.x;
  const int tid = threadIdx.x;
  __shared__ float zsb[64 * 65];
  for (int i = tid; i < 4096; i += 256) {
    const int tt = i >> 6, d = i & 63;
    zsb[tt * 65 + d] = z_all[((size_t)tt * 256 + b) * 64 + d];
  }
  __syncthreads();
  const int n = tid & 63, tg = tid >> 6;
  for (int tt = tg; tt < 64; tt += 4) {
    float s = 0.0f;
    #pragma unroll
    for (int d = 0; d < 64; ++d) s += zsb[tt * 65 + d] * zsb[n * 65 + d];
    z_gram[((size_t)b * 64 + tt) * 64 + n] = s;
  }
}

// ---------------------------------------------------------------------------
// scan step kernel S_t: grid (16bt x 16jt -> blockIdx = bt*16+jt), 256 thr.
// Phase A (redundant per b-slice of 16): LSTM elementwise from Gin -> h,
// C update (Cin->Cout dbuf), distributed kw/y dots + local g, softmax from
// z_gram, memory read -> kx. [kx|h] kept in LDS xsT[577][18] (k-major).
// Phase B: Gout[b-slice][j-slice 128] = xsT^T @ WT[:,j-slice].
// Races removed by G/C double buffering; MkT col-t torn-read harmless (x0).
// ---------------------------------------------------------------------------
__global__ __launch_bounds__(256) void scan_step_kernel(
    const int t,
    const float* __restrict__ Gin, float* __restrict__ Gout,
    const float* __restrict__ bsum,
    const float* __restrict__ Cin, float* __restrict__ Cout,
    const float* __restrict__ z_gram, float* __restrict__ MkT,
    float* __restrict__ out, const float* __restrict__ WT,
    const float* __restrict__ out_w, const float* __restrict__ out_b,
    const float* __restrict__ gate_w, const float* __restrict__ gate_b,
    const float* __restrict__ key_w, const float* __restrict__ key_b,
    const float* __restrict__ conf_w, const float* __restrict__ conf_b)
{
  __shared__ __align__(16) float xsT[577 * 18];   // [k][16b + 2 pad]
  __shared__ __align__(16) float wks[16 * 64];    // [b][n]
  __shared__ float sgs[16], kx64s[16];

  const int bx  = blockIdx.x;
  const int bt  = bx >> 4;
  const int jt  = bx & 15;
  const int b0  = bt * 16;
  const int tid = threadIdx.x;
  const int lane = tid & 63, wid = tid >> 6;

  // ---- A1: LSTM elementwise (16 b x 512 j)
  for (int i = tid; i < 16 * 512; i += 256) {
    const int b = i >> 9, j = i & 511;
    float gv[4];
    #pragma unroll
    for (int g = 0; g < 4; ++g) {
      float s = bsum[g * 512 + j];
      if (t > 0) s += Gin[(size_t)(b0 + b) * 2048 + g * 512 + j];
      gv[g] = s;
    }
    const size_t cidx = (size_t)(b0 + b) * 512 + j;
    const float c2v = sigm(gv[1]) * Cin[cidx] + sigm(gv[0]) * tanhf(gv[2]);
    Cout[cidx] = c2v;
    xsT[(65 + j) * 18 + b] = sigm(gv[3]) * tanhf(c2v);
  }
  __syncthreads();

  // ---- A2: dots. local list: kw {jt,16+jt,32+jt,48+jt}, y (jt<4: 64+jt), g(68)
  for (int task = wid; task < 96; task += 4) {
    const int dd = task >> 4, b = task & 15;
    if (dd == 4 && jt >= 4) continue;
    const int d = (dd < 4) ? dd * 16 + jt : ((dd == 4) ? 64 + jt : 68);
    const float* row = (d < 64) ? (key_w + (size_t)d * 512)
                     : (d < 68) ? (out_w + (size_t)(d - 64) * 512)
                                : gate_w;
    float a = 0.0f;
    #pragma unroll
    for (int kk = 0; kk < 8; ++kk)
      a += xsT[(65 + lane + kk * 64) * 18 + b] * row[lane + kk * 64];
    #pragma unroll
    for (int m = 32; m > 0; m >>= 1) a += __shfl_xor(a, m);
    if (lane == 0) {
      if (d < 64)      MkT[(size_t)(b0 + b) * 4096 + d * 64 + t] = a + key_b[d];
      else if (d < 68) out[(size_t)t * 1024 + (b0 + b) * 4 + (d - 64)] = a + out_b[d - 64];
      else             sgs[b] = sigm(a + gate_b[0]);
    }
  }

  // ---- A3: softmax per b (4 b's per wave)
  if (t > 0) {
    const float cw = conf_w[0], cb = conf_b[0];
    for (int b = wid; b < 16; b += 4) {
      const float sim = z_gram[((size_t)(b0 + b) * 64 + t) * 64 + lane];
      const bool valid = (lane < t);
      float mx = valid ? sim : -3.0e38f;
      #pragma unroll
      for (int m = 32; m > 0; m >>= 1) mx = fmaxf(mx, __shfl_xor(mx, m));
      const float p = valid ? expf(sim - mx) : 0.0f;
      float sum = p;
      #pragma unroll
      for (int m = 32; m > 0; m >>= 1) sum += __shfl_xor(sum, m);
      const float wk = p / sum;
      wks[b * 64 + lane] = wk;
      float kc = wk * sigm(sim * cw + cb);
      #pragma unroll
      for (int m = 32; m > 0; m >>= 1) kc += __shfl_xor(kc, m);
      if (lane == 0) kx64s[b] = kc;
    }
  }
  __syncthreads();

  // ---- A4: memory read -> xsT rows 0..64 (kx)
  if (t == 0) {
    for (int i = tid; i < 65 * 16; i += 256) xsT[(i >> 4) * 18 + (i & 15)] = 0.0f;
  } else {
    const int d = tid & 63, bg = tid >> 6;
    #pragma unroll
    for (int ii = 0; ii < 4; ++ii) {
      const int b = bg * 4 + ii;
      const float* mr = MkT + (size_t)(b0 + b) * 4096 + d * 64;
      const float* wr = wks + b * 64;
      float a = 0.0f;
      #pragma unroll
      for (int q = 0; q < 16; ++q) {
        const float4 m4 = *(const float4*)(mr + 4 * q);
        const float4 w4 = *(const float4*)(wr + 4 * q);
        a += m4.x * w4.x + m4.y * w4.y + m4.z * w4.z + m4.w * w4.w;
      }
      xsT[d * 18 + b] = sgs[b] * a;
    }
    if (tid < 16) xsT[64 * 18 + tid] = sgs[tid] * kx64s[tid];
  }
  __syncthreads();

  // ---- B: gates GEMM for step t+1: Gout[b0..b0+16][jt*128..+128]
  {
    const int tj = tid & 31, tb = tid >> 5;        // 32 lanes x 4j; 8 grp x 2b
    const int j0 = jt * 128 + tj * 4;
    float acc[2][4];
    #pragma unroll
    for (int i = 0; i < 2; ++i) { acc[i][0]=0.f; acc[i][1]=0.f; acc[i][2]=0.f; acc[i][3]=0.f; }
    const float* wp = WT + j0;
    #pragma unroll 4
    for (int k = 0; k < 577; ++k) {
      const float4 w = *(const float4*)(wp + (size_t)k * 2048);
      const float2 x = *(const float2*)(&xsT[k * 18 + tb * 2]);
      acc[0][0] += x.x * w.x; acc[0][1] += x.x * w.y; acc[0][2] += x.x * w.z; acc[0][3] += x.x * w.w;
      acc[1][0] += x.y * w.x; acc[1][1] += x.y * w.y; acc[1][2] += x.y * w.z; acc[1][3] += x.y * w.w;
    }
    #pragma unroll
    for (int i = 0; i < 2; ++i) {
      float4 r; r.x = acc[i][0]; r.y = acc[i][1]; r.z = acc[i][2]; r.w = acc[i][3];
      *(float4*)(Gout + (size_t)(b0 + tb * 2 + i) * 2048 + j0) = r;
    }
  }
}

// ---------------------------------------------------------------------------
extern "C" void kernel_launch(void* const* d_in, const int* in_sizes, int n_in,
                              void* d_out, int out_size, void* d_ws, size_t ws_size,
                              hipStream_t stream) {
  const float* images = (const float*)d_in[0];
  const float* w1     = (const float*)d_in[1];
  const float* b1     = (const float*)d_in[2];
  const float* w2     = (const float*)d_in[3];
  const float* b2     = (const float*)d_in[4];
  const float* w3     = (const float*)d_in[5];
  const float* b3     = (const float*)d_in[6];
  const float* ew     = (const float*)d_in[7];
  const float* eb     = (const float*)d_in[8];
  const float* w_ih   = (const float*)d_in[9];
  const float* w_hh   = (const float*)d_in[10];
  const float* b_ih   = (const float*)d_in[11];
  const float* b_hh   = (const float*)d_in[12];
  const float* out_w  = (const float*)d_in[13];
  const float* out_b  = (const float*)d_in[14];
  const float* gate_w = (const float*)d_in[15];
  const float* gate_b = (const float*)d_in[16];
  const float* key_w  = (const float*)d_in[17];
  const float* key_b  = (const float*)d_in[18];
  const float* conf_w = (const float*)d_in[19];
  const float* conf_b = (const float*)d_in[20];
  float* out = (float*)d_out;
  float* ws  = (float*)d_ws;

  // ws layout (floats)
  float* WT     = ws;                  // 1,187,840
  float* bsum   = ws + 1187840;        // 2,048
  float* w1T    = ws + 1189888;        // 1,536
  float* w2T    = ws + 1191424;        // 32,768
  float* w3T    = ws + 1224192;        // 65,536
  float* ewT    = ws + 1289728;        // 16,384
  float* z_all  = ws + 1306112;        // 1,048,576
  float* MkT    = ws + 2354688;        // 1,048,576
  float* C0     = ws + 3403264;        // 131,072
  float* C1     = ws + 3534336;        // 131,072
  float* z_gram = ws + 3665408;        // 1,048,576
  float* G0     = ws + 4713984;        // 524,288
  float* G1     = ws + 5238272;        // 524,288
  const size_t baseF = 5762560;        // c1g starts here
  float* c1g = ws + baseF;
  const size_t availF = (ws_size / 4 > baseF) ? (ws_size / 4 - baseF) : 0;
  long chunkL = (long)(availF / 7680ull);
  int chunk = (chunkL > 16384) ? 16384 : (int)chunkL;

  hipMemsetAsync(C0, 0, 131072 * sizeof(float), stream);

  prep_kernel<<<(PREP_N + 255) / 256, 256, 0, stream>>>(
      w_ih, w_hh, b_ih, b_hh, w1, w2, w3, ew, WT, bsum, w1T, w2T, w3T, ewT);

  if (chunk >= 2048) {
    for (int s0 = 0; s0 < 16384; s0 += chunk) {
      const int n = (16384 - s0 < chunk) ? (16384 - s0) : chunk;
      conv1_kernel<<<n, ENT, 0, stream>>>(images, w1T, b1, c1g, s0);
      enc2_kernel<<<n, ENT, 0, stream>>>(c1g, w2T, b2, w3T, b3, ewT, eb, z_all, s0);
    }
  } else {
    encoder_kernel<<<16384, ENT, 0, stream>>>(images, w1T, b1, w2T, b2, w3T, b3, ewT, eb, z_all);
  }

  gram_kernel<<<256, 256, 0, stream>>>(z_all, z_gram);

  for (int t = 0; t < 64; ++t) {
    const float* Gin  = (t & 1) ? G1 : G0;
    float*       Gout = (t & 1) ? G0 : G1;
    const float* Cin  = (t & 1) ? C1 : C0;
    float*       Cout = (t & 1) ? C0 : C1;
    scan_step_kernel<<<256, 256, 0, stream>>>(
        t, Gin, Gout, bsum, Cin, Cout, z_gram, MkT, out, WT,
        out_w, out_b, gate_w, gate_b, key_w, key_b, conf_w, conf_b);
  }
}